// Round 14
// baseline (467.618 us; speedup 1.0000x reference)
//
#include <hip/hip_runtime.h>

// Fused entmax(alpha=1.3) attention, fp32. B=16, N=2048, D=64.
// R18: R17 (206us main, DPP solver) + phase-1 staging DELETED. Audit showed
// the B-frag each lane read from LDS (K[kap][ks*32+lg*8..+8]) is 16
// contiguous bf16 in global, and one load instruction's 64 lanes cover
// 16 full 64B lines -- identical L2 coalescing to the staged path. So
// stage->barrier->ds_read was pure overhead: load B-frags DIRECTLY from
// Khi/Klo planes. Phase 1 = barrier-free {4 loads, 6 MFMA} x16 per wave;
// L2 latency hidden by TLP (barriers were what defeated it). Barriers
// 40 -> 8 per block (exchange only). Arithmetic bit-identical to R17.
// Solver/writeback/PV/fallback = R17 verbatim (DPP reductions).

#define NBATCH 16
#define NSEQ   2048
#define DHEAD  64
#define OUT_OFF (NBATCH * NSEQ * DHEAD)   // out first, attn second
#define INV_A    3.3333333f               // 1/(alpha-1)
#define INV_A_M1 2.3333333f

typedef float  vfloat4 __attribute__((ext_vector_type(4)));
typedef float  f32x4   __attribute__((ext_vector_type(4)));
typedef short  bf16x8  __attribute__((ext_vector_type(8)));
typedef unsigned short u16x8 __attribute__((ext_vector_type(8)));

__device__ __forceinline__ float fast_log2(float x) { return __builtin_amdgcn_logf(x); }
__device__ __forceinline__ float fast_exp2(float x) { return __builtin_amdgcn_exp2f(x); }

__device__ __forceinline__ unsigned bf16_rne(float x) {
    const unsigned u = __float_as_uint(x);
    return (u + 0x7FFFu + ((u >> 16) & 1u)) >> 16;
}

// ---- DPP wave64 reductions (register-lane ops; no LDS/ds_bpermute) ----
template <int CTRL>
__device__ __forceinline__ float dpp_addf(float x) {
    const int t = __builtin_amdgcn_update_dpp(0, __float_as_int(x), CTRL, 0xf, 0xf, true);
    return x + __int_as_float(t);
}
template <int CTRL>
__device__ __forceinline__ float dpp_maxf(float x) {
    const int t = __builtin_amdgcn_update_dpp(__float_as_int(x), __float_as_int(x), CTRL, 0xf, 0xf, false);
    return fmaxf(x, __int_as_float(t));
}
__device__ __forceinline__ float wave_sum64(float x) {
    x = dpp_addf<0xB1>(x);
    x = dpp_addf<0x4E>(x);
    x = dpp_addf<0x141>(x);
    x = dpp_addf<0x140>(x);
    x = dpp_addf<0x142>(x);
    x = dpp_addf<0x143>(x);
    return __int_as_float(__builtin_amdgcn_readlane(__float_as_int(x), 63));
}
__device__ __forceinline__ float wave_max64(float x) {
    x = dpp_maxf<0xB1>(x);
    x = dpp_maxf<0x4E>(x);
    x = dpp_maxf<0x141>(x);
    x = dpp_maxf<0x140>(x);
    x = dpp_maxf<0x142>(x);
    x = dpp_maxf<0x143>(x);
    return __int_as_float(__builtin_amdgcn_readlane(__float_as_int(x), 63));
}

// ---------- pre-kernel: split K into bf16 hi/lo planes in workspace ----------
__global__ __launch_bounds__(256) void ksplit_kernel(
    const float* __restrict__ K, unsigned short* __restrict__ Khi,
    unsigned short* __restrict__ Klo)
{
    const size_t idx = (size_t)blockIdx.x * 256 + threadIdx.x;  // float4 index
    const float4 x = ((const float4*)K)[idx];
    const float xs[4] = {x.x, x.y, x.z, x.w};
    unsigned short h[4], l[4];
    #pragma unroll
    for (int i = 0; i < 4; ++i) {
        const unsigned hr = bf16_rne(xs[i]);
        h[i] = (unsigned short)hr;
        l[i] = (unsigned short)bf16_rne(xs[i] - __uint_as_float(hr << 16));
    }
    ((ushort4*)Khi)[idx] = make_ushort4(h[0], h[1], h[2], h[3]);
    ((ushort4*)Klo)[idx] = make_ushort4(l[0], l[1], l[2], l[3]);
}

// ------------------------------ main kernel ---------------------------------
__global__ __launch_bounds__(512) void entmax_attn_kernel(
    const float* __restrict__ Q, const float* __restrict__ V,
    float* __restrict__ Out,
    const unsigned short* __restrict__ Khi, const unsigned short* __restrict__ Klo)
{
    // reg0 (32 KB): xbuf[16][512] during exchange, then per-wave prow.
    // cvx (16 KB): per wave 512 floats: cval0[128], cidx0[128], cval1[128], cidx1[128].
    __shared__ __align__(16) float reg0[8192];
    __shared__ __align__(16) float cvx[8 * 512];

    const int tid  = threadIdx.x;
    const int w    = tid >> 6;        // 0..7
    const int lane = tid & 63;
    const int arow = lane & 15;       // MFMA row / col lane index
    const int lg   = lane >> 4;       // lane group 0..3

    // XCD pinning: batch b -> XCD b%8
    const int i   = blockIdx.x;       // 0..2047
    const int xcd = i & 7;
    const int j2  = i >> 3;           // 0..255
    const int b   = xcd + 8 * (j2 & 1);
    const int rb  = j2 >> 1;          // 0..127
    const int n0  = rb * 16;          // 16 q-rows per block

    const float* Vb = V + (size_t)b * NSEQ * DHEAD;
    const unsigned short* KhiB = Khi + (size_t)b * NSEQ * DHEAD;
    const unsigned short* KloB = Klo + (size_t)b * NSEQ * DHEAD;

    // ---- A fragments: Q rows in registers (scale 1/8 folded in) ----
    bf16x8 a_hi[2], a_lo[2];
    {
        const float* qrow = Q + ((size_t)b * NSEQ + (size_t)(n0 + arow)) * DHEAD;
        #pragma unroll
        for (int ks = 0; ks < 2; ++ks) {
            const int d0 = ks * 32 + lg * 8;
            const float4 x0 = *(const float4*)(qrow + d0);
            const float4 x1 = *(const float4*)(qrow + d0 + 4);
            const float xs[8] = {x0.x, x0.y, x0.z, x0.w, x1.x, x1.y, x1.z, x1.w};
            #pragma unroll
            for (int e = 0; e < 8; ++e) {
                const float xq = xs[e] * 0.125f;
                const unsigned hr = bf16_rne(xq);
                a_hi[ks][e] = (short)hr;
                a_lo[ks][e] = (short)bf16_rne(xq - __uint_as_float(hr << 16));
            }
        }
    }

    float s[2][32];
    const int kap = 16 * w + arow;          // this wave's key within a tile

    // ---- 4 groups of 512 keys (4 tiles of 128); B-frags direct from global --
    #pragma unroll
    for (int g = 0; g < 4; ++g) {
        f32x4 acc[4];
        #pragma unroll
        for (int tt = 0; tt < 4; ++tt) acc[tt] = (f32x4){0.f, 0.f, 0.f, 0.f};

        #pragma unroll
        for (int tt = 0; tt < 4; ++tt) {
            const int t = 4 * g + tt;
            // key row for this lane: t*128 + kap; frag = 8 contiguous bf16
            const size_t kb = (size_t)(t * 128 + kap) * DHEAD + lg * 8;
            const bf16x8 bh0 = *(const bf16x8*)(KhiB + kb);
            const bf16x8 bh1 = *(const bf16x8*)(KhiB + kb + 32);
            const bf16x8 bl0 = *(const bf16x8*)(KloB + kb);
            const bf16x8 bl1 = *(const bf16x8*)(KloB + kb + 32);
            acc[tt] = __builtin_amdgcn_mfma_f32_16x16x32_bf16(a_hi[0], bh0, acc[tt], 0, 0, 0);
            acc[tt] = __builtin_amdgcn_mfma_f32_16x16x32_bf16(a_hi[0], bl0, acc[tt], 0, 0, 0);
            acc[tt] = __builtin_amdgcn_mfma_f32_16x16x32_bf16(a_lo[0], bh0, acc[tt], 0, 0, 0);
            acc[tt] = __builtin_amdgcn_mfma_f32_16x16x32_bf16(a_hi[1], bh1, acc[tt], 0, 0, 0);
            acc[tt] = __builtin_amdgcn_mfma_f32_16x16x32_bf16(a_hi[1], bl1, acc[tt], 0, 0, 0);
            acc[tt] = __builtin_amdgcn_mfma_f32_16x16x32_bf16(a_lo[1], bh1, acc[tt], 0, 0, 0);
        }

        // ---- exchange: C frags -> per-wave rows via xbuf[16][512] ----
        // C layout (m89): col(key-in-16) = lane&15, row = lg*4 + reg.
        __syncthreads();   // prev group's xbuf reads done
        #pragma unroll
        for (int tt = 0; tt < 4; ++tt)
            #pragma unroll
            for (int i2 = 0; i2 < 4; ++i2)
                reg0[(lg * 4 + i2) * 512 + tt * 128 + kap] = acc[tt][i2];
        __syncthreads();
        #pragma unroll
        for (int r = 0; r < 2; ++r)
            #pragma unroll
            for (int jj = 0; jj < 8; ++jj)
                s[r][8 * g + jj] = reg0[(2 * w + r) * 512 + jj * 64 + lane];
    }
    __syncthreads();   // all xbuf reads done; reg0 becomes per-wave prow

    float* prow  = reg0 + w * 1024;
    float* cval0 = cvx + w * 512;
    float* cidx0 = cval0 + 128;
    float* cval1 = cval0 + 256;
    float* cidx1 = cval0 + 384;
    const unsigned long long lt_mask = (1ull << lane) - 1ull;
    const int na = n0 + 2 * w;

    // ---- dual row max (DPP) ----
    float mx0 = s[0][0], mx1 = s[1][0];
    #pragma unroll
    for (int j = 1; j < 32; ++j) { mx0 = fmaxf(mx0, s[0][j]); mx1 = fmaxf(mx1, s[1][j]); }
    mx0 = wave_max64(mx0);
    mx1 = wave_max64(mx1);
    #pragma unroll
    for (int j = 0; j < 32; ++j) { s[0][j] -= mx0; s[1][j] -= mx1; }

    // ---- dual ballot-compaction ----
    int base0 = 0, base1 = 0;
    #pragma unroll
    for (int j = 0; j < 32; ++j) {
        const bool a0 = s[0][j] > -1.0f;
        const bool a1 = s[1][j] > -1.0f;
        const unsigned long long bm0 = __ballot(a0);
        const unsigned long long bm1 = __ballot(a1);
        const int q0 = base0 + __popcll(bm0 & lt_mask);
        const int q1 = base1 + __popcll(bm1 & lt_mask);
        if (a0 && q0 < 128) { cval0[q0] = s[0][j]; cidx0[q0] = (float)(j * 64 + lane); }
        if (a1 && q1 < 128) { cval1[q1] = s[1][j]; cidx1[q1] = (float)(j * 64 + lane); }
        base0 += __popcll(bm0);
        base1 += __popcll(bm1);
    }
    const int A0 = base0, A1 = base1;       // wave-uniform

    float* arow0 = Out + OUT_OFF + ((size_t)b * NSEQ + na) * NSEQ;
    float* arow1 = arow0 + NSEQ;

    if (A0 <= 128 && A1 <= 128) {
        // ================= dual sparse solver (common case) =================
        const float cv00 = cval0[lane], cv01 = cval0[64 + lane];
        const float cv10 = cval1[lane], cv11 = cval1[64 + lane];
        const bool ok00 = lane < A0, ok01 = 64 + lane < A0;
        const bool ok10 = lane < A1, ok11 = 64 + lane < A1;

        float lo0 = -1.0f, hi0 = -1e-6f, lo1 = -1.0f, hi1 = -1e-6f;
        #pragma unroll 1
        for (int it = 0; it < 12; ++it) {
            const float ta = 0.5f * (lo0 + hi0);
            const float tb = 0.5f * (lo1 + hi1);
            const float t00 = cv00 - ta, t01 = cv01 - ta;
            const float t10 = cv10 - tb, t11 = cv11 - tb;
            float S0 = ((ok00 && t00 > 0.f) ? fast_exp2(INV_A * fast_log2(t00)) : 0.f)
                     + ((ok01 && t01 > 0.f) ? fast_exp2(INV_A * fast_log2(t01)) : 0.f);
            float S1 = ((ok10 && t10 > 0.f) ? fast_exp2(INV_A * fast_log2(t10)) : 0.f)
                     + ((ok11 && t11 > 0.f) ? fast_exp2(INV_A * fast_log2(t11)) : 0.f);
            S0 = wave_sum64(S0);
            S1 = wave_sum64(S1);
            if (S0 > 1.f) lo0 = ta; else hi0 = ta;
            if (S1 > 1.f) lo1 = tb; else hi1 = tb;
        }
        float tau0 = lo0, tau1 = lo1;
        #pragma unroll 1
        for (int it = 0; it < 2; ++it) {
            const float t00 = cv00 - tau0, t01 = cv01 - tau0;
            const float t10 = cv10 - tau1, t11 = cv11 - tau1;
            float Sa0 = 0.f, Sb0 = 0.f, Sa1 = 0.f, Sb1 = 0.f;
            if (ok00 && t00 > 0.f) { const float l = fast_log2(t00); Sa0 += fast_exp2(INV_A * l); Sb0 += fast_exp2(INV_A_M1 * l); }
            if (ok01 && t01 > 0.f) { const float l = fast_log2(t01); Sa0 += fast_exp2(INV_A * l); Sb0 += fast_exp2(INV_A_M1 * l); }
            if (ok10 && t10 > 0.f) { const float l = fast_log2(t10); Sa1 += fast_exp2(INV_A * l); Sb1 += fast_exp2(INV_A_M1 * l); }
            if (ok11 && t11 > 0.f) { const float l = fast_log2(t11); Sa1 += fast_exp2(INV_A * l); Sb1 += fast_exp2(INV_A_M1 * l); }
            Sa0 = wave_sum64(Sa0);
            Sb0 = wave_sum64(Sb0);
            Sa1 = wave_sum64(Sa1);
            Sb1 = wave_sum64(Sb1);
            tau0 += (Sa0 - 1.f) / (INV_A * Sb0);
            tau0 = fmaxf(fminf(tau0, hi0), lo0);
            tau1 += (Sa1 - 1.f) / (INV_A * Sb1);
            tau1 = fmaxf(fminf(tau1, hi1), lo1);
        }

        // final p + dual normalize
        const float t00 = cv00 - tau0, t01 = cv01 - tau0;
        const float t10 = cv10 - tau1, t11 = cv11 - tau1;
        float p00 = (ok00 && t00 > 0.f) ? fast_exp2(INV_A * fast_log2(t00)) : 0.f;
        float p01 = (ok01 && t01 > 0.f) ? fast_exp2(INV_A * fast_log2(t01)) : 0.f;
        float p10 = (ok10 && t10 > 0.f) ? fast_exp2(INV_A * fast_log2(t10)) : 0.f;
        float p11 = (ok11 && t11 > 0.f) ? fast_exp2(INV_A * fast_log2(t11)) : 0.f;
        float S0 = wave_sum64(p00 + p01);
        float S1 = wave_sum64(p10 + p11);
        const float rn0 = 1.f / (S0 + 1e-12f);
        const float rn1 = 1.f / (S1 + 1e-12f);
        p00 *= rn0; p01 *= rn0; p10 *= rn1; p11 *= rn1;
        const int i00 = ok00 ? (int)cidx0[lane] : 0;
        const int i01 = ok01 ? (int)cidx0[64 + lane] : 0;
        const int i10 = ok10 ? (int)cidx1[lane] : 0;
        const int i11 = ok11 ? (int)cidx1[64 + lane] : 0;
        if (ok00) cval0[lane] = p00;         // cval now holds normalized p
        if (ok01) cval0[64 + lane] = p01;
        if (ok10) cval1[lane] = p10;
        if (ok11) cval1[64 + lane] = p11;

        // ---- attn rows: zeros + scatter via prow, vectorized writeback ----
        #pragma unroll
        for (int seg = 0; seg < 2; ++seg) {
            #pragma unroll
            for (int z = 0; z < 4; ++z)
                *(float4*)&prow[(z * 64 + lane) * 4] = make_float4(0.f, 0.f, 0.f, 0.f);
            if (ok00 && (i00 >> 10) == seg) prow[i00 & 1023] = p00;
            if (ok01 && (i01 >> 10) == seg) prow[i01 & 1023] = p01;
            #pragma unroll
            for (int z = 0; z < 4; ++z) {
                const vfloat4 pv = *(const vfloat4*)&prow[(z * 64 + lane) * 4];
                __builtin_nontemporal_store(pv,
                    (vfloat4*)&arow0[seg * 1024 + (z * 64 + lane) * 4]);
            }
        }
        #pragma unroll
        for (int seg = 0; seg < 2; ++seg) {
            #pragma unroll
            for (int z = 0; z < 4; ++z)
                *(float4*)&prow[(z * 64 + lane) * 4] = make_float4(0.f, 0.f, 0.f, 0.f);
            if (ok10 && (i10 >> 10) == seg) prow[i10 & 1023] = p10;
            if (ok11 && (i11 >> 10) == seg) prow[i11 & 1023] = p11;
            #pragma unroll
            for (int z = 0; z < 4; ++z) {
                const vfloat4 pv = *(const vfloat4*)&prow[(z * 64 + lane) * 4];
                __builtin_nontemporal_store(pv,
                    (vfloat4*)&arow1[seg * 1024 + (z * 64 + lane) * 4]);
            }
        }

        // ---- sparse PV, unroll 8 (8 scattered V loads in flight) ----
        float out0 = 0.f, out1 = 0.f;
        int ii = 0;
        #pragma unroll 1
        for (; ii + 8 <= A0; ii += 8) {
            const float pa = cval0[ii+0], pb = cval0[ii+1], pc = cval0[ii+2], pd = cval0[ii+3];
            const float pe = cval0[ii+4], pf = cval0[ii+5], pg = cval0[ii+6], ph = cval0[ii+7];
            const int ma = (int)cidx0[ii+0], mb = (int)cidx0[ii+1], mc = (int)cidx0[ii+2], md = (int)cidx0[ii+3];
            const int me = (int)cidx0[ii+4], mf = (int)cidx0[ii+5], mg = (int)cidx0[ii+6], mh = (int)cidx0[ii+7];
            out0 += pa * Vb[(size_t)ma * DHEAD + lane] + pb * Vb[(size_t)mb * DHEAD + lane]
                  + pc * Vb[(size_t)mc * DHEAD + lane] + pd * Vb[(size_t)md * DHEAD + lane]
                  + pe * Vb[(size_t)me * DHEAD + lane] + pf * Vb[(size_t)mf * DHEAD + lane]
                  + pg * Vb[(size_t)mg * DHEAD + lane] + ph * Vb[(size_t)mh * DHEAD + lane];
        }
        #pragma unroll 1
        for (; ii < A0; ++ii)
            out0 += cval0[ii] * Vb[(size_t)(int)cidx0[ii] * DHEAD + lane];

        int jj = 0;
        #pragma unroll 1
        for (; jj + 8 <= A1; jj += 8) {
            const float pa = cval1[jj+0], pb = cval1[jj+1], pc = cval1[jj+2], pd = cval1[jj+3];
            const float pe = cval1[jj+4], pf = cval1[jj+5], pg = cval1[jj+6], ph = cval1[jj+7];
            const int ma = (int)cidx1[jj+0], mb = (int)cidx1[jj+1], mc = (int)cidx1[jj+2], md = (int)cidx1[jj+3];
            const int me = (int)cidx1[jj+4], mf = (int)cidx1[jj+5], mg = (int)cidx1[jj+6], mh = (int)cidx1[jj+7];
            out1 += pa * Vb[(size_t)ma * DHEAD + lane] + pb * Vb[(size_t)mb * DHEAD + lane]
                  + pc * Vb[(size_t)mc * DHEAD + lane] + pd * Vb[(size_t)md * DHEAD + lane]
                  + pe * Vb[(size_t)me * DHEAD + lane] + pf * Vb[(size_t)mf * DHEAD + lane]
                  + pg * Vb[(size_t)mg * DHEAD + lane] + ph * Vb[(size_t)mh * DHEAD + lane];
        }
        #pragma unroll 1
        for (; jj < A1; ++jj)
            out1 += cval1[jj] * Vb[(size_t)(int)cidx1[jj] * DHEAD + lane];

        Out[((size_t)b * NSEQ + na) * DHEAD + lane] = out0;
        Out[((size_t)b * NSEQ + na + 1) * DHEAD + lane] = out1;
    } else {
        // ============== fallback: per-row path (rare; correctness) ==========
        #pragma unroll
        for (int r = 0; r < 2; ++r) {
            const int A = r ? A1 : A0;
            float* cval = r ? cval1 : cval0;
            float* cidx = r ? cidx1 : cidx0;
            float* arowX = r ? arow1 : arow0;
            float outacc = 0.f;

            if (A <= 128) {
                const float cv0 = cval[lane];
                const float cv1 = cval[64 + lane];
                const bool ok0 = (lane < A);
                const bool ok1 = (64 + lane < A);

                float lo = -1.0f, hi = -1e-6f;
                #pragma unroll 1
                for (int it = 0; it < 12; ++it) {
                    const float tau = 0.5f * (lo + hi);
                    const float t0 = cv0 - tau, t1 = cv1 - tau;
                    float S = ((ok0 && t0 > 0.f) ? fast_exp2(INV_A * fast_log2(t0)) : 0.f)
                            + ((ok1 && t1 > 0.f) ? fast_exp2(INV_A * fast_log2(t1)) : 0.f);
                    S = wave_sum64(S);
                    if (S > 1.f) lo = tau; else hi = tau;
                }
                float tau = lo;
                #pragma unroll 1
                for (int it = 0; it < 2; ++it) {
                    const float t0 = cv0 - tau, t1 = cv1 - tau;
                    float S1 = 0.f, S2 = 0.f;
                    if (ok0 && t0 > 0.f) {
                        const float l = fast_log2(t0);
                        S1 += fast_exp2(INV_A * l); S2 += fast_exp2(INV_A_M1 * l);
                    }
                    if (ok1 && t1 > 0.f) {
                        const float l = fast_log2(t1);
                        S1 += fast_exp2(INV_A * l); S2 += fast_exp2(INV_A_M1 * l);
                    }
                    S1 = wave_sum64(S1);
                    S2 = wave_sum64(S2);
                    tau += (S1 - 1.f) / (INV_A * S2);
                    tau = fmaxf(fminf(tau, hi), lo);
                }

                const float t0 = cv0 - tau, t1 = cv1 - tau;
                float p0 = (ok0 && t0 > 0.f) ? fast_exp2(INV_A * fast_log2(t0)) : 0.f;
                float p1 = (ok1 && t1 > 0.f) ? fast_exp2(INV_A * fast_log2(t1)) : 0.f;
                const float S = wave_sum64(p0 + p1);
                const float rnorm = 1.f / (S + 1e-12f);
                p0 *= rnorm; p1 *= rnorm;
                const int i0 = ok0 ? (int)cidx[lane] : 0;
                const int i1 = ok1 ? (int)cidx[64 + lane] : 0;
                if (ok0) cval[lane] = p0;
                if (ok1) cval[64 + lane] = p1;

                #pragma unroll
                for (int seg = 0; seg < 2; ++seg) {
                    #pragma unroll
                    for (int z = 0; z < 4; ++z)
                        *(float4*)&prow[(z * 64 + lane) * 4] = make_float4(0.f, 0.f, 0.f, 0.f);
                    if (ok0 && (i0 >> 10) == seg) prow[i0 & 1023] = p0;
                    if (ok1 && (i1 >> 10) == seg) prow[i1 & 1023] = p1;
                    #pragma unroll
                    for (int z = 0; z < 4; ++z) {
                        const vfloat4 pv = *(const vfloat4*)&prow[(z * 64 + lane) * 4];
                        __builtin_nontemporal_store(pv,
                            (vfloat4*)&arowX[seg * 1024 + (z * 64 + lane) * 4]);
                    }
                }

                int ii = 0;
                #pragma unroll 1
                for (; ii + 4 <= A; ii += 4) {
                    const float pa = cval[ii + 0], pb = cval[ii + 1];
                    const float pc = cval[ii + 2], pd = cval[ii + 3];
                    const int ma = (int)cidx[ii + 0], mb = (int)cidx[ii + 1];
                    const int mc = (int)cidx[ii + 2], md = (int)cidx[ii + 3];
                    outacc += pa * Vb[(size_t)ma * DHEAD + lane]
                            + pb * Vb[(size_t)mb * DHEAD + lane]
                            + pc * Vb[(size_t)mc * DHEAD + lane]
                            + pd * Vb[(size_t)md * DHEAD + lane];
                }
                #pragma unroll 1
                for (; ii < A; ++ii)
                    outacc += cval[ii] * Vb[(size_t)(int)cidx[ii] * DHEAD + lane];
            } else {
                // dense fallback on MFMA scores (register-lean; ~never taken)
                float lo = -1.0f, hi = -1e-6f;
                #pragma unroll 1
                for (int it = 0; it < 12; ++it) {
                    const float tau = 0.5f * (lo + hi);
                    float S = 0.f;
                    #pragma unroll
                    for (int j = 0; j < 32; ++j) {
                        const float t = s[r][j] - tau;
                        const float p = fast_exp2(INV_A * fast_log2(t));
                        S += (t > 0.f) ? p : 0.f;
                    }
                    S = wave_sum64(S);
                    if (S > 1.f) lo = tau; else hi = tau;
                }
                float tau = lo;
                #pragma unroll 1
                for (int it = 0; it < 2; ++it) {
                    float S1 = 0.f, S2 = 0.f;
                    #pragma unroll
                    for (int j = 0; j < 32; ++j) {
                        const float t = s[r][j] - tau;
                        if (t > 0.f) {
                            const float l = fast_log2(t);
                            S1 += fast_exp2(INV_A * l); S2 += fast_exp2(INV_A_M1 * l);
                        }
                    }
                    S1 = wave_sum64(S1);
                    S2 = wave_sum64(S2);
                    tau += (S1 - 1.f) / (INV_A * S2);
                    tau = fmaxf(fminf(tau, hi), lo);
                }
                float S = 0.f;
                #pragma unroll
                for (int j = 0; j < 32; ++j) {
                    const float t = s[r][j] - tau;
                    const float p = (t > 0.f) ? fast_exp2(INV_A * fast_log2(t)) : 0.f;
                    s[r][j] = p;
                    S += p;
                }
                S = wave_sum64(S);
                const float rnorm = 1.f / (S + 1e-12f);

                #pragma unroll
                for (int seg = 0; seg < 2; ++seg) {
                    #pragma unroll
                    for (int jj = 0; jj < 16; ++jj)
                        prow[jj * 64 + lane] = s[r][seg * 16 + jj] * rnorm;
                    #pragma unroll
                    for (int z = 0; z < 16; ++z)
                        __builtin_nontemporal_store(prow[z * 64 + lane],
                                                    &arowX[seg * 1024 + z * 64 + lane]);
                    #pragma unroll 4
                    for (int m = 0; m < 1024; ++m)
                        outacc += prow[m] * Vb[(size_t)(seg * 1024 + m) * DHEAD + lane];
                }
            }

            Out[((size_t)b * NSEQ + (na + r)) * DHEAD + lane] = outacc;
        }
    }
}

extern "C" void kernel_launch(void* const* d_in, const int* in_sizes, int n_in,
                              void* d_out, int out_size, void* d_ws, size_t ws_size,
                              hipStream_t stream) {
    const float* q = (const float*)d_in[0];
    const float* k = (const float*)d_in[1];
    const float* v = (const float*)d_in[2];
    float* out = (float*)d_out;
    (void)in_sizes; (void)n_in; (void)out_size; (void)ws_size;

    unsigned short* Khi = (unsigned short*)d_ws;                       // 4 MB
    unsigned short* Klo = Khi + (size_t)NBATCH * NSEQ * DHEAD;         // +4 MB

    hipLaunchKernelGGL(ksplit_kernel, dim3(2048), dim3(256), 0, stream, k, Khi, Klo);
    hipLaunchKernelGGL(entmax_attn_kernel, dim3(2048), dim3(512), 0, stream,
                       q, v, out, Khi, Klo);
}

// Round 15
// 414.236 us; speedup vs baseline: 1.1289x; 1.1289x over previous
//
#include <hip/hip_runtime.h>

// Fused entmax(alpha=1.3) attention, fp32. B=16, N=2048, D=64.
// R19: R17 (best: 206us) with phase-1 WORK cut, structure untouched.
// R18 proved staging+barriers beat direct-global (247 vs 206) -- latency
// must be paid cooperatively once, not per-wave in the MFMA chain. So keep
// R17's staged loop and instead: (1) drop the Klo plane: (Qhi+Qlo).Khi =
// Q.Khi exactly; dropped term Q.(K-Khi)/8 ~ 2e-3 per score (threshold
// 9.4e-2, measured 1.6e-2). Halves staging loads/stores/ds_reads (and
// bank conflicts), MFMAs 6->4/tile, ksplit halves. (2) bisect 12->8 +2
// Newton (R10-R12 passed with this). DPP reductions kept (R17's +24us win).

#define NBATCH 16
#define NSEQ   2048
#define DHEAD  64
#define OUT_OFF (NBATCH * NSEQ * DHEAD)   // out first, attn second
#define INV_A    3.3333333f               // 1/(alpha-1)
#define INV_A_M1 2.3333333f

typedef float  vfloat4 __attribute__((ext_vector_type(4)));
typedef float  f32x4   __attribute__((ext_vector_type(4)));
typedef short  bf16x8  __attribute__((ext_vector_type(8)));
typedef unsigned short u16x8 __attribute__((ext_vector_type(8)));

__device__ __forceinline__ float fast_log2(float x) { return __builtin_amdgcn_logf(x); }
__device__ __forceinline__ float fast_exp2(float x) { return __builtin_amdgcn_exp2f(x); }

__device__ __forceinline__ unsigned bf16_rne(float x) {
    const unsigned u = __float_as_uint(x);
    return (u + 0x7FFFu + ((u >> 16) & 1u)) >> 16;
}

// ---- DPP wave64 reductions (register-lane ops; no LDS/ds_bpermute) ----
template <int CTRL>
__device__ __forceinline__ float dpp_addf(float x) {
    const int t = __builtin_amdgcn_update_dpp(0, __float_as_int(x), CTRL, 0xf, 0xf, true);
    return x + __int_as_float(t);
}
template <int CTRL>
__device__ __forceinline__ float dpp_maxf(float x) {
    const int t = __builtin_amdgcn_update_dpp(__float_as_int(x), __float_as_int(x), CTRL, 0xf, 0xf, false);
    return fmaxf(x, __int_as_float(t));
}
__device__ __forceinline__ float wave_sum64(float x) {
    x = dpp_addf<0xB1>(x);
    x = dpp_addf<0x4E>(x);
    x = dpp_addf<0x141>(x);
    x = dpp_addf<0x140>(x);
    x = dpp_addf<0x142>(x);
    x = dpp_addf<0x143>(x);
    return __int_as_float(__builtin_amdgcn_readlane(__float_as_int(x), 63));
}
__device__ __forceinline__ float wave_max64(float x) {
    x = dpp_maxf<0xB1>(x);
    x = dpp_maxf<0x4E>(x);
    x = dpp_maxf<0x141>(x);
    x = dpp_maxf<0x140>(x);
    x = dpp_maxf<0x142>(x);
    x = dpp_maxf<0x143>(x);
    return __int_as_float(__builtin_amdgcn_readlane(__float_as_int(x), 63));
}

// ---------- pre-kernel: K -> bf16 hi plane in workspace (lo dropped) --------
__global__ __launch_bounds__(256) void ksplit_kernel(
    const float* __restrict__ K, unsigned short* __restrict__ Khi)
{
    const size_t idx = (size_t)blockIdx.x * 256 + threadIdx.x;  // float4 index
    const float4 x = ((const float4*)K)[idx];
    ((ushort4*)Khi)[idx] = make_ushort4(
        (unsigned short)bf16_rne(x.x), (unsigned short)bf16_rne(x.y),
        (unsigned short)bf16_rne(x.z), (unsigned short)bf16_rne(x.w));
}

// ------------------------------ main kernel ---------------------------------
__global__ __launch_bounds__(512) void entmax_attn_kernel(
    const float* __restrict__ Q, const float* __restrict__ V,
    float* __restrict__ Out, const unsigned short* __restrict__ Khi)
{
    // reg0 (32 KB): phase1 staging (hi tile 16K in first half), then
    //               xbuf[16][512], then per-wave prow (1024 floats each).
    // cvx (16 KB): per wave 512 floats: cval0[128], cidx0[128], cval1[128], cidx1[128].
    __shared__ __align__(16) float reg0[8192];
    __shared__ __align__(16) float cvx[8 * 512];

    const int tid  = threadIdx.x;
    const int w    = tid >> 6;        // 0..7
    const int lane = tid & 63;
    const int arow = lane & 15;       // MFMA row / col lane index
    const int lg   = lane >> 4;       // lane group 0..3

    // XCD pinning: batch b -> XCD b%8
    const int i   = blockIdx.x;       // 0..2047
    const int xcd = i & 7;
    const int j2  = i >> 3;           // 0..255
    const int b   = xcd + 8 * (j2 & 1);
    const int rb  = j2 >> 1;          // 0..127
    const int n0  = rb * 16;          // 16 q-rows per block

    const float* Vb = V + (size_t)b * NSEQ * DHEAD;
    const unsigned short* KhiB = Khi + (size_t)b * NSEQ * DHEAD;
    char* ldsHi = (char*)reg0;

    // ---- A fragments: Q rows in registers (scale 1/8 folded in) ----
    bf16x8 a_hi[2], a_lo[2];
    {
        const float* qrow = Q + ((size_t)b * NSEQ + (size_t)(n0 + arow)) * DHEAD;
        #pragma unroll
        for (int ks = 0; ks < 2; ++ks) {
            const int d0 = ks * 32 + lg * 8;
            const float4 x0 = *(const float4*)(qrow + d0);
            const float4 x1 = *(const float4*)(qrow + d0 + 4);
            const float xs[8] = {x0.x, x0.y, x0.z, x0.w, x1.x, x1.y, x1.z, x1.w};
            #pragma unroll
            for (int e = 0; e < 8; ++e) {
                const float xq = xs[e] * 0.125f;
                const unsigned hr = bf16_rne(xq);
                a_hi[ks][e] = (short)hr;
                a_lo[ks][e] = (short)bf16_rne(xq - __uint_as_float(hr << 16));
            }
        }
    }

    float s[2][32];
    const int kap = 16 * w + arow;          // this wave's key within a tile

    // ---- staging thread geometry (hi plane only: 16 KB/tile) ----
    const int keyA = tid >> 3, cA = tid & 7;
    const int keyB = keyA + 64;
    const size_t gA = (size_t)keyA * DHEAD + cA * 8;
    const size_t gB = (size_t)keyB * DHEAD + cA * 8;
    const int ofA = keyA * 128 + ((cA ^ (keyA & 7)) << 4);
    const int ofB = keyB * 128 + ((cA ^ (keyA & 7)) << 4);

    // prologue: prefetch tile 0 into regs
    u16x8 shA = *(const u16x8*)(KhiB + gA);
    u16x8 shB = *(const u16x8*)(KhiB + gB);

    // ---- 4 groups of 512 keys (4 tiles of 128); ALL STATIC ----
    #pragma unroll
    for (int g = 0; g < 4; ++g) {
        f32x4 acc[4];
        #pragma unroll
        for (int tt = 0; tt < 4; ++tt) acc[tt] = (f32x4){0.f, 0.f, 0.f, 0.f};

        #pragma unroll
        for (int tt = 0; tt < 4; ++tt) {
            const int t = 4 * g + tt;
            __syncthreads();
            *(u16x8*)(ldsHi + ofA) = shA;
            *(u16x8*)(ldsHi + ofB) = shB;
            __syncthreads();

            #pragma unroll
            for (int ks = 0; ks < 2; ++ks) {
                const int loff = kap * 128 + ((((ks << 2) | lg) ^ (kap & 7)) << 4);
                const bf16x8 bh = *(const bf16x8*)(ldsHi + loff);
                acc[tt] = __builtin_amdgcn_mfma_f32_16x16x32_bf16(a_hi[ks], bh, acc[tt], 0, 0, 0);
                acc[tt] = __builtin_amdgcn_mfma_f32_16x16x32_bf16(a_lo[ks], bh, acc[tt], 0, 0, 0);
            }
            if (t < 15) {
                const size_t tb = (size_t)(t + 1) * (128 * DHEAD);
                shA = *(const u16x8*)(KhiB + tb + gA);
                shB = *(const u16x8*)(KhiB + tb + gB);
            }
        }

        // ---- exchange: C frags -> per-wave rows via xbuf[16][512] ----
        // C layout (m89): col(key-in-16) = lane&15, row = lg*4 + reg.
        __syncthreads();
        #pragma unroll
        for (int tt = 0; tt < 4; ++tt)
            #pragma unroll
            for (int i2 = 0; i2 < 4; ++i2)
                reg0[(lg * 4 + i2) * 512 + tt * 128 + kap] = acc[tt][i2];
        __syncthreads();
        #pragma unroll
        for (int r = 0; r < 2; ++r)
            #pragma unroll
            for (int jj = 0; jj < 8; ++jj)
                s[r][8 * g + jj] = reg0[(2 * w + r) * 512 + jj * 64 + lane];
    }
    __syncthreads();   // all xbuf reads done; reg0 becomes per-wave prow

    float* prow  = reg0 + w * 1024;
    float* cval0 = cvx + w * 512;
    float* cidx0 = cval0 + 128;
    float* cval1 = cval0 + 256;
    float* cidx1 = cval0 + 384;
    const unsigned long long lt_mask = (1ull << lane) - 1ull;
    const int na = n0 + 2 * w;

    // ---- dual row max (DPP) ----
    float mx0 = s[0][0], mx1 = s[1][0];
    #pragma unroll
    for (int j = 1; j < 32; ++j) { mx0 = fmaxf(mx0, s[0][j]); mx1 = fmaxf(mx1, s[1][j]); }
    mx0 = wave_max64(mx0);
    mx1 = wave_max64(mx1);
    #pragma unroll
    for (int j = 0; j < 32; ++j) { s[0][j] -= mx0; s[1][j] -= mx1; }

    // ---- dual ballot-compaction ----
    int base0 = 0, base1 = 0;
    #pragma unroll
    for (int j = 0; j < 32; ++j) {
        const bool a0 = s[0][j] > -1.0f;
        const bool a1 = s[1][j] > -1.0f;
        const unsigned long long bm0 = __ballot(a0);
        const unsigned long long bm1 = __ballot(a1);
        const int q0 = base0 + __popcll(bm0 & lt_mask);
        const int q1 = base1 + __popcll(bm1 & lt_mask);
        if (a0 && q0 < 128) { cval0[q0] = s[0][j]; cidx0[q0] = (float)(j * 64 + lane); }
        if (a1 && q1 < 128) { cval1[q1] = s[1][j]; cidx1[q1] = (float)(j * 64 + lane); }
        base0 += __popcll(bm0);
        base1 += __popcll(bm1);
    }
    const int A0 = base0, A1 = base1;       // wave-uniform

    float* arow0 = Out + OUT_OFF + ((size_t)b * NSEQ + na) * NSEQ;
    float* arow1 = arow0 + NSEQ;

    if (A0 <= 128 && A1 <= 128) {
        // ================= dual sparse solver (common case) =================
        const float cv00 = cval0[lane], cv01 = cval0[64 + lane];
        const float cv10 = cval1[lane], cv11 = cval1[64 + lane];
        const bool ok00 = lane < A0, ok01 = 64 + lane < A0;
        const bool ok10 = lane < A1, ok11 = 64 + lane < A1;

        float lo0 = -1.0f, hi0 = -1e-6f, lo1 = -1.0f, hi1 = -1e-6f;
        #pragma unroll 1
        for (int it = 0; it < 8; ++it) {
            const float ta = 0.5f * (lo0 + hi0);
            const float tb = 0.5f * (lo1 + hi1);
            const float t00 = cv00 - ta, t01 = cv01 - ta;
            const float t10 = cv10 - tb, t11 = cv11 - tb;
            float S0 = ((ok00 && t00 > 0.f) ? fast_exp2(INV_A * fast_log2(t00)) : 0.f)
                     + ((ok01 && t01 > 0.f) ? fast_exp2(INV_A * fast_log2(t01)) : 0.f);
            float S1 = ((ok10 && t10 > 0.f) ? fast_exp2(INV_A * fast_log2(t10)) : 0.f)
                     + ((ok11 && t11 > 0.f) ? fast_exp2(INV_A * fast_log2(t11)) : 0.f);
            S0 = wave_sum64(S0);
            S1 = wave_sum64(S1);
            if (S0 > 1.f) lo0 = ta; else hi0 = ta;
            if (S1 > 1.f) lo1 = tb; else hi1 = tb;
        }
        float tau0 = lo0, tau1 = lo1;
        #pragma unroll 1
        for (int it = 0; it < 2; ++it) {
            const float t00 = cv00 - tau0, t01 = cv01 - tau0;
            const float t10 = cv10 - tau1, t11 = cv11 - tau1;
            float Sa0 = 0.f, Sb0 = 0.f, Sa1 = 0.f, Sb1 = 0.f;
            if (ok00 && t00 > 0.f) { const float l = fast_log2(t00); Sa0 += fast_exp2(INV_A * l); Sb0 += fast_exp2(INV_A_M1 * l); }
            if (ok01 && t01 > 0.f) { const float l = fast_log2(t01); Sa0 += fast_exp2(INV_A * l); Sb0 += fast_exp2(INV_A_M1 * l); }
            if (ok10 && t10 > 0.f) { const float l = fast_log2(t10); Sa1 += fast_exp2(INV_A * l); Sb1 += fast_exp2(INV_A_M1 * l); }
            if (ok11 && t11 > 0.f) { const float l = fast_log2(t11); Sa1 += fast_exp2(INV_A * l); Sb1 += fast_exp2(INV_A_M1 * l); }
            Sa0 = wave_sum64(Sa0);
            Sb0 = wave_sum64(Sb0);
            Sa1 = wave_sum64(Sa1);
            Sb1 = wave_sum64(Sb1);
            tau0 += (Sa0 - 1.f) / (INV_A * Sb0);
            tau0 = fmaxf(fminf(tau0, hi0), lo0);
            tau1 += (Sa1 - 1.f) / (INV_A * Sb1);
            tau1 = fmaxf(fminf(tau1, hi1), lo1);
        }

        // final p + dual normalize
        const float t00 = cv00 - tau0, t01 = cv01 - tau0;
        const float t10 = cv10 - tau1, t11 = cv11 - tau1;
        float p00 = (ok00 && t00 > 0.f) ? fast_exp2(INV_A * fast_log2(t00)) : 0.f;
        float p01 = (ok01 && t01 > 0.f) ? fast_exp2(INV_A * fast_log2(t01)) : 0.f;
        float p10 = (ok10 && t10 > 0.f) ? fast_exp2(INV_A * fast_log2(t10)) : 0.f;
        float p11 = (ok11 && t11 > 0.f) ? fast_exp2(INV_A * fast_log2(t11)) : 0.f;
        float S0 = wave_sum64(p00 + p01);
        float S1 = wave_sum64(p10 + p11);
        const float rn0 = 1.f / (S0 + 1e-12f);
        const float rn1 = 1.f / (S1 + 1e-12f);
        p00 *= rn0; p01 *= rn0; p10 *= rn1; p11 *= rn1;
        const int i00 = ok00 ? (int)cidx0[lane] : 0;
        const int i01 = ok01 ? (int)cidx0[64 + lane] : 0;
        const int i10 = ok10 ? (int)cidx1[lane] : 0;
        const int i11 = ok11 ? (int)cidx1[64 + lane] : 0;
        if (ok00) cval0[lane] = p00;         // cval now holds normalized p
        if (ok01) cval0[64 + lane] = p01;
        if (ok10) cval1[lane] = p10;
        if (ok11) cval1[64 + lane] = p11;

        // ---- attn rows: zeros + scatter via prow, vectorized writeback ----
        #pragma unroll
        for (int seg = 0; seg < 2; ++seg) {
            #pragma unroll
            for (int z = 0; z < 4; ++z)
                *(float4*)&prow[(z * 64 + lane) * 4] = make_float4(0.f, 0.f, 0.f, 0.f);
            if (ok00 && (i00 >> 10) == seg) prow[i00 & 1023] = p00;
            if (ok01 && (i01 >> 10) == seg) prow[i01 & 1023] = p01;
            #pragma unroll
            for (int z = 0; z < 4; ++z) {
                const vfloat4 pv = *(const vfloat4*)&prow[(z * 64 + lane) * 4];
                __builtin_nontemporal_store(pv,
                    (vfloat4*)&arow0[seg * 1024 + (z * 64 + lane) * 4]);
            }
        }
        #pragma unroll
        for (int seg = 0; seg < 2; ++seg) {
            #pragma unroll
            for (int z = 0; z < 4; ++z)
                *(float4*)&prow[(z * 64 + lane) * 4] = make_float4(0.f, 0.f, 0.f, 0.f);
            if (ok10 && (i10 >> 10) == seg) prow[i10 & 1023] = p10;
            if (ok11 && (i11 >> 10) == seg) prow[i11 & 1023] = p11;
            #pragma unroll
            for (int z = 0; z < 4; ++z) {
                const vfloat4 pv = *(const vfloat4*)&prow[(z * 64 + lane) * 4];
                __builtin_nontemporal_store(pv,
                    (vfloat4*)&arow1[seg * 1024 + (z * 64 + lane) * 4]);
            }
        }

        // ---- sparse PV, unroll 8 (8 scattered V loads in flight) ----
        float out0 = 0.f, out1 = 0.f;
        int ii = 0;
        #pragma unroll 1
        for (; ii + 8 <= A0; ii += 8) {
            const float pa = cval0[ii+0], pb = cval0[ii+1], pc = cval0[ii+2], pd = cval0[ii+3];
            const float pe = cval0[ii+4], pf = cval0[ii+5], pg = cval0[ii+6], ph = cval0[ii+7];
            const int ma = (int)cidx0[ii+0], mb = (int)cidx0[ii+1], mc = (int)cidx0[ii+2], md = (int)cidx0[ii+3];
            const int me = (int)cidx0[ii+4], mf = (int)cidx0[ii+5], mg = (int)cidx0[ii+6], mh = (int)cidx0[ii+7];
            out0 += pa * Vb[(size_t)ma * DHEAD + lane] + pb * Vb[(size_t)mb * DHEAD + lane]
                  + pc * Vb[(size_t)mc * DHEAD + lane] + pd * Vb[(size_t)md * DHEAD + lane]
                  + pe * Vb[(size_t)me * DHEAD + lane] + pf * Vb[(size_t)mf * DHEAD + lane]
                  + pg * Vb[(size_t)mg * DHEAD + lane] + ph * Vb[(size_t)mh * DHEAD + lane];
        }
        #pragma unroll 1
        for (; ii < A0; ++ii)
            out0 += cval0[ii] * Vb[(size_t)(int)cidx0[ii] * DHEAD + lane];

        int jj = 0;
        #pragma unroll 1
        for (; jj + 8 <= A1; jj += 8) {
            const float pa = cval1[jj+0], pb = cval1[jj+1], pc = cval1[jj+2], pd = cval1[jj+3];
            const float pe = cval1[jj+4], pf = cval1[jj+5], pg = cval1[jj+6], ph = cval1[jj+7];
            const int ma = (int)cidx1[jj+0], mb = (int)cidx1[jj+1], mc = (int)cidx1[jj+2], md = (int)cidx1[jj+3];
            const int me = (int)cidx1[jj+4], mf = (int)cidx1[jj+5], mg = (int)cidx1[jj+6], mh = (int)cidx1[jj+7];
            out1 += pa * Vb[(size_t)ma * DHEAD + lane] + pb * Vb[(size_t)mb * DHEAD + lane]
                  + pc * Vb[(size_t)mc * DHEAD + lane] + pd * Vb[(size_t)md * DHEAD + lane]
                  + pe * Vb[(size_t)me * DHEAD + lane] + pf * Vb[(size_t)mf * DHEAD + lane]
                  + pg * Vb[(size_t)mg * DHEAD + lane] + ph * Vb[(size_t)mh * DHEAD + lane];
        }
        #pragma unroll 1
        for (; jj < A1; ++jj)
            out1 += cval1[jj] * Vb[(size_t)(int)cidx1[jj] * DHEAD + lane];

        Out[((size_t)b * NSEQ + na) * DHEAD + lane] = out0;
        Out[((size_t)b * NSEQ + na + 1) * DHEAD + lane] = out1;
    } else {
        // ============== fallback: per-row path (rare; correctness) ==========
        #pragma unroll
        for (int r = 0; r < 2; ++r) {
            const int A = r ? A1 : A0;
            float* cval = r ? cval1 : cval0;
            float* cidx = r ? cidx1 : cidx0;
            float* arowX = r ? arow1 : arow0;
            float outacc = 0.f;

            if (A <= 128) {
                const float cv0 = cval[lane];
                const float cv1 = cval[64 + lane];
                const bool ok0 = (lane < A);
                const bool ok1 = (64 + lane < A);

                float lo = -1.0f, hi = -1e-6f;
                #pragma unroll 1
                for (int it = 0; it < 12; ++it) {
                    const float tau = 0.5f * (lo + hi);
                    const float t0 = cv0 - tau, t1 = cv1 - tau;
                    float S = ((ok0 && t0 > 0.f) ? fast_exp2(INV_A * fast_log2(t0)) : 0.f)
                            + ((ok1 && t1 > 0.f) ? fast_exp2(INV_A * fast_log2(t1)) : 0.f);
                    S = wave_sum64(S);
                    if (S > 1.f) lo = tau; else hi = tau;
                }
                float tau = lo;
                #pragma unroll 1
                for (int it = 0; it < 2; ++it) {
                    const float t0 = cv0 - tau, t1 = cv1 - tau;
                    float S1 = 0.f, S2 = 0.f;
                    if (ok0 && t0 > 0.f) {
                        const float l = fast_log2(t0);
                        S1 += fast_exp2(INV_A * l); S2 += fast_exp2(INV_A_M1 * l);
                    }
                    if (ok1 && t1 > 0.f) {
                        const float l = fast_log2(t1);
                        S1 += fast_exp2(INV_A * l); S2 += fast_exp2(INV_A_M1 * l);
                    }
                    S1 = wave_sum64(S1);
                    S2 = wave_sum64(S2);
                    tau += (S1 - 1.f) / (INV_A * S2);
                    tau = fmaxf(fminf(tau, hi), lo);
                }

                const float t0 = cv0 - tau, t1 = cv1 - tau;
                float p0 = (ok0 && t0 > 0.f) ? fast_exp2(INV_A * fast_log2(t0)) : 0.f;
                float p1 = (ok1 && t1 > 0.f) ? fast_exp2(INV_A * fast_log2(t1)) : 0.f;
                const float S = wave_sum64(p0 + p1);
                const float rnorm = 1.f / (S + 1e-12f);
                p0 *= rnorm; p1 *= rnorm;
                const int i0 = ok0 ? (int)cidx[lane] : 0;
                const int i1 = ok1 ? (int)cidx[64 + lane] : 0;
                if (ok0) cval[lane] = p0;
                if (ok1) cval[64 + lane] = p1;

                #pragma unroll
                for (int seg = 0; seg < 2; ++seg) {
                    #pragma unroll
                    for (int z = 0; z < 4; ++z)
                        *(float4*)&prow[(z * 64 + lane) * 4] = make_float4(0.f, 0.f, 0.f, 0.f);
                    if (ok0 && (i0 >> 10) == seg) prow[i0 & 1023] = p0;
                    if (ok1 && (i1 >> 10) == seg) prow[i1 & 1023] = p1;
                    #pragma unroll
                    for (int z = 0; z < 4; ++z) {
                        const vfloat4 pv = *(const vfloat4*)&prow[(z * 64 + lane) * 4];
                        __builtin_nontemporal_store(pv,
                            (vfloat4*)&arowX[seg * 1024 + (z * 64 + lane) * 4]);
                    }
                }

                int ii = 0;
                #pragma unroll 1
                for (; ii + 4 <= A; ii += 4) {
                    const float pa = cval[ii + 0], pb = cval[ii + 1];
                    const float pc = cval[ii + 2], pd = cval[ii + 3];
                    const int ma = (int)cidx[ii + 0], mb = (int)cidx[ii + 1];
                    const int mc = (int)cidx[ii + 2], md = (int)cidx[ii + 3];
                    outacc += pa * Vb[(size_t)ma * DHEAD + lane]
                            + pb * Vb[(size_t)mb * DHEAD + lane]
                            + pc * Vb[(size_t)mc * DHEAD + lane]
                            + pd * Vb[(size_t)md * DHEAD + lane];
                }
                #pragma unroll 1
                for (; ii < A; ++ii)
                    outacc += cval[ii] * Vb[(size_t)(int)cidx[ii] * DHEAD + lane];
            } else {
                // dense fallback on MFMA scores (register-lean; ~never taken)
                float lo = -1.0f, hi = -1e-6f;
                #pragma unroll 1
                for (int it = 0; it < 12; ++it) {
                    const float tau = 0.5f * (lo + hi);
                    float S = 0.f;
                    #pragma unroll
                    for (int j = 0; j < 32; ++j) {
                        const float t = s[r][j] - tau;
                        const float p = fast_exp2(INV_A * fast_log2(t));
                        S += (t > 0.f) ? p : 0.f;
                    }
                    S = wave_sum64(S);
                    if (S > 1.f) lo = tau; else hi = tau;
                }
                float tau = lo;
                #pragma unroll 1
                for (int it = 0; it < 2; ++it) {
                    float S1 = 0.f, S2 = 0.f;
                    #pragma unroll
                    for (int j = 0; j < 32; ++j) {
                        const float t = s[r][j] - tau;
                        if (t > 0.f) {
                            const float l = fast_log2(t);
                            S1 += fast_exp2(INV_A * l); S2 += fast_exp2(INV_A_M1 * l);
                        }
                    }
                    S1 = wave_sum64(S1);
                    S2 = wave_sum64(S2);
                    tau += (S1 - 1.f) / (INV_A * S2);
                    tau = fmaxf(fminf(tau, hi), lo);
                }
                float S = 0.f;
                #pragma unroll
                for (int j = 0; j < 32; ++j) {
                    const float t = s[r][j] - tau;
                    const float p = (t > 0.f) ? fast_exp2(INV_A * fast_log2(t)) : 0.f;
                    s[r][j] = p;
                    S += p;
                }
                S = wave_sum64(S);
                const float rnorm = 1.f / (S + 1e-12f);

                #pragma unroll
                for (int seg = 0; seg < 2; ++seg) {
                    #pragma unroll
                    for (int jj = 0; jj < 16; ++jj)
                        prow[jj * 64 + lane] = s[r][seg * 16 + jj] * rnorm;
                    #pragma unroll
                    for (int z = 0; z < 16; ++z)
                        __builtin_nontemporal_store(prow[z * 64 + lane],
                                                    &arowX[seg * 1024 + z * 64 + lane]);
                    #pragma unroll 4
                    for (int m = 0; m < 1024; ++m)
                        outacc += prow[m] * Vb[(size_t)(seg * 1024 + m) * DHEAD + lane];
                }
            }

            Out[((size_t)b * NSEQ + (na + r)) * DHEAD + lane] = outacc;
        }
    }
}

extern "C" void kernel_launch(void* const* d_in, const int* in_sizes, int n_in,
                              void* d_out, int out_size, void* d_ws, size_t ws_size,
                              hipStream_t stream) {
    const float* q = (const float*)d_in[0];
    const float* k = (const float*)d_in[1];
    const float* v = (const float*)d_in[2];
    float* out = (float*)d_out;
    (void)in_sizes; (void)n_in; (void)out_size; (void)ws_size;

    unsigned short* Khi = (unsigned short*)d_ws;                       // 4 MB

    hipLaunchKernelGGL(ksplit_kernel, dim3(2048), dim3(256), 0, stream, k, Khi);
    hipLaunchKernelGGL(entmax_attn_kernel, dim3(2048), dim3(512), 0, stream,
                       q, v, out, Khi);
}